// Round 2
// baseline (745.549 us; speedup 1.0000x reference)
//
#include <hip/hip_runtime.h>
#include <hip/hip_bf16.h>
#include <cmath>
#include <stdint.h>

#define B_ 2
#define S_ 2048
#define D_ 2048
#define H_ 16
#define HKV_ 2
#define DH_ 128
#define G_ 8
#define DKV_ 256   // HKV*DH
#define MROWS_ (B_ * S_)   // 4096

typedef _Float16 f16;
typedef _Float16 f16x8 __attribute__((ext_vector_type(8)));
typedef _Float16 f16x4 __attribute__((ext_vector_type(4)));
typedef float f32x4 __attribute__((ext_vector_type(4)));

__device__ __forceinline__ void gload_lds16(const void* g, void* lds) {
  __builtin_amdgcn_global_load_lds((const __attribute__((address_space(1))) void*)g,
                                   (__attribute__((address_space(3))) void*)lds,
                                   16, 0, 0);
}

__global__ void cast_kernel(const float* __restrict__ in, f16* __restrict__ out, int n4) {
  int i = blockIdx.x * blockDim.x + threadIdx.x;
  int stride = gridDim.x * blockDim.x;
  for (; i < n4; i += stride) {
    float4 v = reinterpret_cast<const float4*>(in)[i];
    f16x4 o = { (f16)v.x, (f16)v.y, (f16)v.z, (f16)v.w };
    reinterpret_cast<f16x4*>(out)[i] = o;
  }
}

// C[m][n] = sum_k A[m][k] * Bm[n][k] + bias[n]
// A: (M,K) f16 row-major, Bm: (N,K) f16 row-major.  M%128==0, N%128==0, K%64==0.
// TRANS=true: write C^T instead -> Ct[n*M + m] (contiguous f16x4 along m).
template<typename OUT_T, bool TRANS>
__global__ __launch_bounds__(256)
void gemm_bt(const f16* __restrict__ A, const f16* __restrict__ Bm,
             const float* __restrict__ bias, OUT_T* __restrict__ C,
             int M, int N, int K) {
  __shared__ __align__(16) f16 sA[128 * 64];
  __shared__ __align__(16) f16 sB[128 * 64];
  const int tid  = threadIdx.x;
  const int lane = tid & 63;
  const int w    = tid >> 6;        // wave 0..3
  const int wr   = w >> 1, wc = w & 1;
  const int r16  = lane & 15, grp = lane >> 4;
  const int bm = blockIdx.y * 128;
  const int bn = blockIdx.x * 128;

  f32x4 acc[4][4] = {};

  for (int k0 = 0; k0 < K; k0 += 64) {
#pragma unroll
    for (int j = 0; j < 4; ++j) {
      int seg = j * 4 + w;
      int e = seg * 512 + lane * 8;
      int r = e >> 6, c = e & 63;
      gload_lds16(A  + (size_t)(bm + r) * K + k0 + c, &sA[seg * 512]);
      gload_lds16(Bm + (size_t)(bn + r) * K + k0 + c, &sB[seg * 512]);
    }
    asm volatile("s_waitcnt vmcnt(0)" ::: "memory");
    __syncthreads();

#pragma unroll
    for (int kk = 0; kk < 64; kk += 32) {
      f16x8 af[4], bf[4];
#pragma unroll
      for (int m = 0; m < 4; ++m)
        af[m] = *reinterpret_cast<const f16x8*>(&sA[(wr * 64 + m * 16 + r16) * 64 + kk + grp * 8]);
#pragma unroll
      for (int n = 0; n < 4; ++n)
        bf[n] = *reinterpret_cast<const f16x8*>(&sB[(wc * 64 + n * 16 + r16) * 64 + kk + grp * 8]);
#pragma unroll
      for (int m = 0; m < 4; ++m)
#pragma unroll
        for (int n = 0; n < 4; ++n)
          acc[m][n] = __builtin_amdgcn_mfma_f32_16x16x32_f16(af[m], bf[n], acc[m][n], 0, 0, 0);
    }
    __syncthreads();
  }

  // epilogue: per 16x16 frag: col = lane&15, row = grp*4 + j
#pragma unroll
  for (int n = 0; n < 4; ++n) {
    int col = bn + wc * 64 + n * 16 + r16;
    float bv = bias ? bias[col] : 0.f;
#pragma unroll
    for (int m = 0; m < 4; ++m) {
      int row0 = bm + wr * 64 + m * 16 + grp * 4;
      if constexpr (TRANS) {
        f16x4 st;
#pragma unroll
        for (int j = 0; j < 4; ++j) st[j] = (f16)(acc[m][n][j] + bv);
        *reinterpret_cast<f16x4*>(&C[(size_t)col * M + row0]) = st;
      } else {
#pragma unroll
        for (int j = 0; j < 4; ++j) {
          float v = acc[m][n][j] + bv;
          C[(size_t)(row0 + j) * N + col] = (OUT_T)v;
        }
      }
    }
  }
}

// Flash attention, causal, GQA. 1 wave per block, 16 q-rows per block, KVBLK=32.
// Q: (B*S, D) f16; K: (B*S, DKV) f16; Vt: (DKV, B*S) f16 (transposed V); O: (B*S, D) f16.
__global__ __launch_bounds__(64)
void attn_kernel(const f16* __restrict__ Q, const f16* __restrict__ K,
                 const f16* __restrict__ Vt, f16* __restrict__ O) {
  const int lane = threadIdx.x;
  const int qi = lane & 15, grp = lane >> 4;
  const int qt = blockIdx.x;       // 16-row q tile
  const int hq = blockIdx.y;       // query head 0..15
  const int b  = blockIdx.z;
  const int kvh = hq >> 3;         // kv head = hq / G
  const float INV_SCALE = 0.08838834764831845f;  // 1/sqrt(128)

  // Q fragments (B-operand of swapped QK^T): lane holds Q[q=qi][d=kd*32+grp*8 ..+7]
  const size_t qbase = ((size_t)(b * S_ + qt * 16 + qi)) * D_ + hq * DH_;
  f16x8 qf[4];
#pragma unroll
  for (int kd = 0; kd < 4; ++kd)
    qf[kd] = *reinterpret_cast<const f16x8*>(Q + qbase + kd * 32 + grp * 8);

  float m = -INFINITY, lsum = 0.f;
  f32x4 accO[8] = {};  // accO[dt][j] = O[q=qi][d = dt*16 + grp*4 + j]

  const int q_lo  = qt * 16;
  const int q_pos = q_lo + qi;
  const f16* Kh  = K  + (size_t)b * S_ * DKV_ + kvh * DH_;
  // V^T element [d][s] at Vth[d * MROWS_ + s]
  const f16* Vth = Vt + (size_t)kvh * DH_ * MROWS_ + (size_t)b * S_;

  // ---- full (unmasked) 32-kv blocks ----
  const int nfull = q_lo >> 5;
  for (int it = 0; it < nfull; ++it) {
    const int kv0 = it * 32;
    f32x4 s0 = {}, s1 = {};
#pragma unroll
    for (int kd = 0; kd < 4; ++kd) {
      f16x8 k0 = *reinterpret_cast<const f16x8*>(Kh + (size_t)(kv0 + qi) * DKV_ + kd * 32 + grp * 8);
      f16x8 k1 = *reinterpret_cast<const f16x8*>(Kh + (size_t)(kv0 + 16 + qi) * DKV_ + kd * 32 + grp * 8);
      s0 = __builtin_amdgcn_mfma_f32_16x16x32_f16(k0, qf[kd], s0, 0, 0, 0);
      s1 = __builtin_amdgcn_mfma_f32_16x16x32_f16(k1, qf[kd], s1, 0, 0, 0);
    }
    float p[8], tm = -INFINITY;
#pragma unroll
    for (int j = 0; j < 4; ++j) {
      p[j]     = s0[j] * INV_SCALE;
      p[4 + j] = s1[j] * INV_SCALE;
    }
#pragma unroll
    for (int i = 0; i < 8; ++i) tm = fmaxf(tm, p[i]);
    tm = fmaxf(tm, __shfl_xor(tm, 16));
    tm = fmaxf(tm, __shfl_xor(tm, 32));
    float scale = 1.f;
    if (!__all(tm <= m + 8.f)) {           // defer-max: rescale only on real growth
      float m_new = fmaxf(m, tm);
      scale = __expf(m - m_new);
      m = m_new;
#pragma unroll
      for (int dt = 0; dt < 8; ++dt)
#pragma unroll
        for (int j = 0; j < 4; ++j) accO[dt][j] *= scale;
    }
    float ps = 0.f;
#pragma unroll
    for (int i = 0; i < 8; ++i) {
      p[i] = __expf(p[i] - m);
      ps += p[i];
    }
    ps += __shfl_xor(ps, 16);
    ps += __shfl_xor(ps, 32);
    lsum = lsum * scale + ps;

    f16x4 pf0 = { (f16)p[0], (f16)p[1], (f16)p[2], (f16)p[3] };
    f16x4 pf1 = { (f16)p[4], (f16)p[5], (f16)p[6], (f16)p[7] };
#pragma unroll
    for (int dt = 0; dt < 8; ++dt) {
      const f16* vrow = Vth + (size_t)(dt * 16 + qi) * MROWS_ + kv0 + grp * 4;
      f16x4 v0 = *reinterpret_cast<const f16x4*>(vrow);
      f16x4 v1 = *reinterpret_cast<const f16x4*>(vrow + 16);
      accO[dt] = __builtin_amdgcn_mfma_f32_16x16x16f16(v0, pf0, accO[dt], 0, 0, 0);
      accO[dt] = __builtin_amdgcn_mfma_f32_16x16x16f16(v1, pf1, accO[dt], 0, 0, 0);
    }
  }

  // ---- tail 16-kv blocks (masked) ----
  for (int kv0 = nfull * 32; kv0 < q_lo + 16; kv0 += 16) {
    f32x4 s = {};
#pragma unroll
    for (int kd = 0; kd < 4; ++kd) {
      f16x8 kf = *reinterpret_cast<const f16x8*>(Kh + (size_t)(kv0 + qi) * DKV_ + kd * 32 + grp * 8);
      s = __builtin_amdgcn_mfma_f32_16x16x32_f16(kf, qf[kd], s, 0, 0, 0);
    }
    float p[4], tm = -INFINITY;
#pragma unroll
    for (int j = 0; j < 4; ++j) {
      float sv = s[j] * INV_SCALE;
      int kv_pos = kv0 + grp * 4 + j;
      sv = (kv_pos > q_pos) ? -INFINITY : sv;
      p[j] = sv;
      tm = fmaxf(tm, sv);
    }
    tm = fmaxf(tm, __shfl_xor(tm, 16));
    tm = fmaxf(tm, __shfl_xor(tm, 32));
    float scale = 1.f;
    if (!__all(tm <= m + 8.f)) {
      float m_new = fmaxf(m, tm);
      scale = __expf(m - m_new);
      m = m_new;
#pragma unroll
      for (int dt = 0; dt < 8; ++dt)
#pragma unroll
        for (int j = 0; j < 4; ++j) accO[dt][j] *= scale;
    }
    float ps = 0.f;
#pragma unroll
    for (int j = 0; j < 4; ++j) {
      p[j] = __expf(p[j] - m);
      ps += p[j];
    }
    ps += __shfl_xor(ps, 16);
    ps += __shfl_xor(ps, 32);
    lsum = lsum * scale + ps;

    f16x4 pf = { (f16)p[0], (f16)p[1], (f16)p[2], (f16)p[3] };
#pragma unroll
    for (int dt = 0; dt < 8; ++dt) {
      f16x4 vf = *reinterpret_cast<const f16x4*>(Vth + (size_t)(dt * 16 + qi) * MROWS_ + kv0 + grp * 4);
      accO[dt] = __builtin_amdgcn_mfma_f32_16x16x16f16(vf, pf, accO[dt], 0, 0, 0);
    }
  }

  float inv_l = 1.f / lsum;
#pragma unroll
  for (int dt = 0; dt < 8; ++dt)
#pragma unroll
    for (int j = 0; j < 4; ++j)
      O[((size_t)(b * S_ + qt * 16 + qi)) * D_ + hq * DH_ + dt * 16 + grp * 4 + j] =
          (f16)(accO[dt][j] * inv_l);
}

extern "C" void kernel_launch(void* const* d_in, const int* in_sizes, int n_in,
                              void* d_out, int out_size, void* d_ws, size_t ws_size,
                              hipStream_t stream) {
  const float* x  = (const float*)d_in[0];
  const float* Wq = (const float*)d_in[1];
  const float* bq = (const float*)d_in[2];
  const float* Wk = (const float*)d_in[3];
  const float* bk = (const float*)d_in[4];
  const float* Wv = (const float*)d_in[5];
  const float* bv = (const float*)d_in[6];
  const float* Wo = (const float*)d_in[7];
  const float* bo = (const float*)d_in[8];
  float* out = (float*)d_out;

  char* ws = (char*)d_ws;
  size_t off = 0;
  auto alloc = [&](size_t bytes) {
    char* p = ws + off;
    off += (bytes + 255) & ~(size_t)255;
    return p;
  };
  f16* xh  = (f16*)alloc((size_t)B_ * S_ * D_ * 2);
  f16* wqh = (f16*)alloc((size_t)D_ * D_ * 2);
  f16* wkh = (f16*)alloc((size_t)DKV_ * D_ * 2);
  f16* wvh = (f16*)alloc((size_t)DKV_ * D_ * 2);
  f16* woh = (f16*)alloc((size_t)D_ * D_ * 2);
  f16* qh  = (f16*)alloc((size_t)B_ * S_ * D_ * 2);
  f16* kh  = (f16*)alloc((size_t)B_ * S_ * DKV_ * 2);
  f16* vth = (f16*)alloc((size_t)B_ * S_ * DKV_ * 2);   // V^T: (DKV, B*S)
  f16* ah  = (f16*)alloc((size_t)B_ * S_ * D_ * 2);

  auto cast = [&](const float* in, f16* o, int n) {
    int n4 = n / 4;
    int grid = (n4 + 255) / 256;
    if (grid > 2048) grid = 2048;
    cast_kernel<<<dim3(grid), dim3(256), 0, stream>>>(in, o, n4);
  };
  cast(x,  xh,  B_ * S_ * D_);
  cast(Wq, wqh, D_ * D_);
  cast(Wk, wkh, DKV_ * D_);
  cast(Wv, wvh, DKV_ * D_);
  cast(Wo, woh, D_ * D_);

  const int M = B_ * S_;
  gemm_bt<f16, false><<<dim3(D_ / 128, M / 128), 256, 0, stream>>>(xh, wqh, bq, qh, M, D_, D_);
  gemm_bt<f16, false><<<dim3(DKV_ / 128, M / 128), 256, 0, stream>>>(xh, wkh, bk, kh, M, DKV_, D_);
  gemm_bt<f16, true ><<<dim3(DKV_ / 128, M / 128), 256, 0, stream>>>(xh, wvh, bv, vth, M, DKV_, D_);

  attn_kernel<<<dim3(S_ / 16, H_, B_), 64, 0, stream>>>(qh, kh, vth, ah);

  gemm_bt<float, false><<<dim3(D_ / 128, M / 128), 256, 0, stream>>>(ah, woh, bo, out, M, D_, D_);
}

// Round 3
// 562.748 us; speedup vs baseline: 1.3248x; 1.3248x over previous
//
#include <hip/hip_runtime.h>
#include <hip/hip_bf16.h>
#include <cmath>
#include <stdint.h>

#define B_ 2
#define S_ 2048
#define D_ 2048
#define H_ 16
#define HKV_ 2
#define DH_ 128
#define G_ 8
#define DKV_ 256   // HKV*DH
#define MROWS_ (B_ * S_)   // 4096

typedef _Float16 f16;
typedef _Float16 f16x8 __attribute__((ext_vector_type(8)));
typedef _Float16 f16x4 __attribute__((ext_vector_type(4)));
typedef float f32x4 __attribute__((ext_vector_type(4)));

__device__ __forceinline__ void gload_lds16(const void* g, void* lds) {
  __builtin_amdgcn_global_load_lds((const __attribute__((address_space(1))) void*)g,
                                   (__attribute__((address_space(3))) void*)lds,
                                   16, 0, 0);
}

__global__ void cast_kernel(const float* __restrict__ in, f16* __restrict__ out, int n4) {
  int i = blockIdx.x * blockDim.x + threadIdx.x;
  int stride = gridDim.x * blockDim.x;
  for (; i < n4; i += stride) {
    float4 v = reinterpret_cast<const float4*>(in)[i];
    f16x4 o = { (f16)v.x, (f16)v.y, (f16)v.z, (f16)v.w };
    reinterpret_cast<f16x4*>(out)[i] = o;
  }
}

// C[m][n] = sum_k A[m][k] * Bm[n][k] + bias[n]
// A: (M,K) f16 row-major, Bm: (N,K) f16 row-major.  M%128==0, N%128==0, K%64==0.
// MODE 0: row-major OUT_T.  MODE 1: kv-interleaved transpose for attention V:
//   element C[m][n] stored at C4[(m>>2)*(N*4) + n*4 + (m&3)]  (f16).
template<typename OUT_T, int MODE>
__global__ __launch_bounds__(256)
void gemm_bt(const f16* __restrict__ A, const f16* __restrict__ Bm,
             const float* __restrict__ bias, OUT_T* __restrict__ C,
             int M, int N, int K) {
  __shared__ __align__(16) f16 sA[128 * 64];
  __shared__ __align__(16) f16 sB[128 * 64];
  const int tid  = threadIdx.x;
  const int lane = tid & 63;
  const int w    = tid >> 6;        // wave 0..3
  const int wr   = w >> 1, wc = w & 1;
  const int r16  = lane & 15, grp = lane >> 4;
  const int bm = blockIdx.y * 128;
  const int bn = blockIdx.x * 128;

  f32x4 acc[4][4] = {};

  for (int k0 = 0; k0 < K; k0 += 64) {
#pragma unroll
    for (int j = 0; j < 4; ++j) {
      int seg = j * 4 + w;
      int e = seg * 512 + lane * 8;
      int r = e >> 6, c = e & 63;
      gload_lds16(A  + (size_t)(bm + r) * K + k0 + c, &sA[seg * 512]);
      gload_lds16(Bm + (size_t)(bn + r) * K + k0 + c, &sB[seg * 512]);
    }
    asm volatile("s_waitcnt vmcnt(0)" ::: "memory");
    __syncthreads();

#pragma unroll
    for (int kk = 0; kk < 64; kk += 32) {
      f16x8 af[4], bf[4];
#pragma unroll
      for (int m = 0; m < 4; ++m)
        af[m] = *reinterpret_cast<const f16x8*>(&sA[(wr * 64 + m * 16 + r16) * 64 + kk + grp * 8]);
#pragma unroll
      for (int n = 0; n < 4; ++n)
        bf[n] = *reinterpret_cast<const f16x8*>(&sB[(wc * 64 + n * 16 + r16) * 64 + kk + grp * 8]);
#pragma unroll
      for (int m = 0; m < 4; ++m)
#pragma unroll
        for (int n = 0; n < 4; ++n)
          acc[m][n] = __builtin_amdgcn_mfma_f32_16x16x32_f16(af[m], bf[n], acc[m][n], 0, 0, 0);
    }
    __syncthreads();
  }

  // epilogue: per 16x16 frag: col = lane&15, row = grp*4 + j
#pragma unroll
  for (int n = 0; n < 4; ++n) {
    int col = bn + wc * 64 + n * 16 + r16;
    float bv = bias ? bias[col] : 0.f;
#pragma unroll
    for (int m = 0; m < 4; ++m) {
      int row0 = bm + wr * 64 + m * 16 + grp * 4;   // 4-aligned
      if constexpr (MODE == 1) {
        f16x4 st;
#pragma unroll
        for (int j = 0; j < 4; ++j) st[j] = (f16)(acc[m][n][j] + bv);
        *reinterpret_cast<f16x4*>(&C[(size_t)(row0 >> 2) * (N * 4) + col * 4]) = st;
      } else {
#pragma unroll
        for (int j = 0; j < 4; ++j) {
          float v = acc[m][n][j] + bv;
          C[(size_t)(row0 + j) * N + col] = (OUT_T)v;
        }
      }
    }
  }
}

// Flash attention, causal, GQA. 256-thread blocks = 4 independent waves, each
// owning one (b, hq, qt) task (16 q-rows), KVBLK=32, branchless online softmax.
// Q: (B*S, D) f16; K: (B*S, DKV) f16;
// V4: kv-interleaved V^T — element V[s][d] at V4[(s>>2)*(DKV*4) + d*4 + (s&3)].
__global__ __launch_bounds__(256)
void attn_kernel(const f16* __restrict__ Q, const f16* __restrict__ K,
                 const f16* __restrict__ V4, f16* __restrict__ O) {
  const int lane = threadIdx.x & 63;
  const int qi = lane & 15, grp = lane >> 4;
  const int t  = blockIdx.x * 4 + (threadIdx.x >> 6);  // 0..4095
  const int b  = t >> 11;
  const int hq = (t >> 7) & 15;
  const int qt = 127 - (t & 127);   // long tasks dispatch first
  const int kvh = hq >> 3;
  const f16 SCL = (f16)0.08838834764831845f;  // 1/sqrt(128)

  // Q fragments (B-operand of swapped QK^T), pre-scaled by 1/sqrt(DH)
  const size_t qbase = ((size_t)(b * S_ + qt * 16 + qi)) * D_ + hq * DH_;
  f16x8 qf[4];
#pragma unroll
  for (int kd = 0; kd < 4; ++kd) {
    qf[kd] = *reinterpret_cast<const f16x8*>(Q + qbase + kd * 32 + grp * 8);
#pragma unroll
    for (int e = 0; e < 8; ++e) qf[kd][e] *= SCL;
  }

  float m = -INFINITY, lsum = 0.f;
  f32x4 accO[8] = {};  // accO[dt][j] = O[q=qi][d = dt*16 + grp*4 + j]

  const int q_lo  = qt * 16;
  const int q_pos = q_lo + qi;
  const f16* Kh = K  + (size_t)b * S_ * DKV_ + kvh * DH_;
  const f16* Vh = V4 + (size_t)b * S_ * DKV_ + kvh * (DH_ * 4);  // + (s>>2)*1024 + dl*4 + (s&3)

  // ---- full (unmasked) 32-kv blocks ----
  const int nfull = q_lo >> 5;
  for (int it = 0; it < nfull; ++it) {
    const int kv0 = it * 32;
    f32x4 s0 = {}, s1 = {};
#pragma unroll
    for (int kd = 0; kd < 4; ++kd) {
      f16x8 k0 = *reinterpret_cast<const f16x8*>(Kh + (size_t)(kv0 + qi) * DKV_ + kd * 32 + grp * 8);
      f16x8 k1 = *reinterpret_cast<const f16x8*>(Kh + (size_t)(kv0 + 16 + qi) * DKV_ + kd * 32 + grp * 8);
      s0 = __builtin_amdgcn_mfma_f32_16x16x32_f16(k0, qf[kd], s0, 0, 0, 0);
      s1 = __builtin_amdgcn_mfma_f32_16x16x32_f16(k1, qf[kd], s1, 0, 0, 0);
    }
    float p[8], tm = -INFINITY;
#pragma unroll
    for (int j = 0; j < 4; ++j) { p[j] = s0[j]; p[4 + j] = s1[j]; }
#pragma unroll
    for (int i = 0; i < 8; ++i) tm = fmaxf(tm, p[i]);
    tm = fmaxf(tm, __shfl_xor(tm, 16));
    tm = fmaxf(tm, __shfl_xor(tm, 32));
    float m_new = fmaxf(m, tm);
    float scale = __expf(m - m_new);
    m = m_new;
    float ps = 0.f;
#pragma unroll
    for (int i = 0; i < 8; ++i) {
      p[i] = __expf(p[i] - m);
      ps += p[i];
    }
    ps += __shfl_xor(ps, 16);
    ps += __shfl_xor(ps, 32);
    lsum = lsum * scale + ps;

    f16x4 pf0 = { (f16)p[0], (f16)p[1], (f16)p[2], (f16)p[3] };
    f16x4 pf1 = { (f16)p[4], (f16)p[5], (f16)p[6], (f16)p[7] };
#pragma unroll
    for (int dt = 0; dt < 8; ++dt) {
      const f16* vp = Vh + (size_t)((kv0 >> 2) + grp) * (DKV_ * 4) + (dt * 16 + qi) * 4;
      f16x4 v0 = *reinterpret_cast<const f16x4*>(vp);
      f16x4 v1 = *reinterpret_cast<const f16x4*>(vp + 4 * DKV_ * 4);  // kv0+16
#pragma unroll
      for (int j = 0; j < 4; ++j) accO[dt][j] *= scale;
      accO[dt] = __builtin_amdgcn_mfma_f32_16x16x16f16(v0, pf0, accO[dt], 0, 0, 0);
      accO[dt] = __builtin_amdgcn_mfma_f32_16x16x16f16(v1, pf1, accO[dt], 0, 0, 0);
    }
  }

  // ---- tail 16-kv blocks (causal-masked) ----
  for (int kv0 = nfull * 32; kv0 < q_lo + 16; kv0 += 16) {
    f32x4 s = {};
#pragma unroll
    for (int kd = 0; kd < 4; ++kd) {
      f16x8 kf = *reinterpret_cast<const f16x8*>(Kh + (size_t)(kv0 + qi) * DKV_ + kd * 32 + grp * 8);
      s = __builtin_amdgcn_mfma_f32_16x16x32_f16(kf, qf[kd], s, 0, 0, 0);
    }
    float p[4], tm = -INFINITY;
#pragma unroll
    for (int j = 0; j < 4; ++j) {
      float sv = s[j];
      int kv_pos = kv0 + grp * 4 + j;
      sv = (kv_pos > q_pos) ? -INFINITY : sv;
      p[j] = sv;
      tm = fmaxf(tm, sv);
    }
    tm = fmaxf(tm, __shfl_xor(tm, 16));
    tm = fmaxf(tm, __shfl_xor(tm, 32));
    float m_new = fmaxf(m, tm);
    float scale = __expf(m - m_new);
    m = m_new;
    float ps = 0.f;
#pragma unroll
    for (int j = 0; j < 4; ++j) {
      p[j] = __expf(p[j] - m);
      ps += p[j];
    }
    ps += __shfl_xor(ps, 16);
    ps += __shfl_xor(ps, 32);
    lsum = lsum * scale + ps;

    f16x4 pf = { (f16)p[0], (f16)p[1], (f16)p[2], (f16)p[3] };
#pragma unroll
    for (int dt = 0; dt < 8; ++dt) {
      const f16* vp = Vh + (size_t)((kv0 >> 2) + grp) * (DKV_ * 4) + (dt * 16 + qi) * 4;
      f16x4 vf = *reinterpret_cast<const f16x4*>(vp);
#pragma unroll
      for (int j = 0; j < 4; ++j) accO[dt][j] *= scale;
      accO[dt] = __builtin_amdgcn_mfma_f32_16x16x16f16(vf, pf, accO[dt], 0, 0, 0);
    }
  }

  float inv_l = 1.f / lsum;
  const size_t obase = ((size_t)(b * S_ + qt * 16 + qi)) * D_ + hq * DH_;
#pragma unroll
  for (int dt = 0; dt < 8; ++dt) {
    f16x4 st;
#pragma unroll
    for (int j = 0; j < 4; ++j) st[j] = (f16)(accO[dt][j] * inv_l);
    *reinterpret_cast<f16x4*>(&O[obase + dt * 16 + grp * 4]) = st;
  }
}

extern "C" void kernel_launch(void* const* d_in, const int* in_sizes, int n_in,
                              void* d_out, int out_size, void* d_ws, size_t ws_size,
                              hipStream_t stream) {
  const float* x  = (const float*)d_in[0];
  const float* Wq = (const float*)d_in[1];
  const float* bq = (const float*)d_in[2];
  const float* Wk = (const float*)d_in[3];
  const float* bk = (const float*)d_in[4];
  const float* Wv = (const float*)d_in[5];
  const float* bv = (const float*)d_in[6];
  const float* Wo = (const float*)d_in[7];
  const float* bo = (const float*)d_in[8];
  float* out = (float*)d_out;

  char* ws = (char*)d_ws;
  size_t off = 0;
  auto alloc = [&](size_t bytes) {
    char* p = ws + off;
    off += (bytes + 255) & ~(size_t)255;
    return p;
  };
  f16* xh  = (f16*)alloc((size_t)B_ * S_ * D_ * 2);
  f16* wqh = (f16*)alloc((size_t)D_ * D_ * 2);
  f16* wkh = (f16*)alloc((size_t)DKV_ * D_ * 2);
  f16* wvh = (f16*)alloc((size_t)DKV_ * D_ * 2);
  f16* woh = (f16*)alloc((size_t)D_ * D_ * 2);
  f16* qh  = (f16*)alloc((size_t)B_ * S_ * D_ * 2);
  f16* kh  = (f16*)alloc((size_t)B_ * S_ * DKV_ * 2);
  f16* v4h = (f16*)alloc((size_t)B_ * S_ * DKV_ * 2);   // kv-interleaved V^T
  f16* ah  = (f16*)alloc((size_t)B_ * S_ * D_ * 2);

  auto cast = [&](const float* in, f16* o, int n) {
    int n4 = n / 4;
    int grid = (n4 + 255) / 256;
    if (grid > 2048) grid = 2048;
    cast_kernel<<<dim3(grid), dim3(256), 0, stream>>>(in, o, n4);
  };
  cast(x,  xh,  B_ * S_ * D_);
  cast(Wq, wqh, D_ * D_);
  cast(Wk, wkh, DKV_ * D_);
  cast(Wv, wvh, DKV_ * D_);
  cast(Wo, woh, D_ * D_);

  const int M = B_ * S_;
  gemm_bt<f16, 0><<<dim3(D_ / 128, M / 128), 256, 0, stream>>>(xh, wqh, bq, qh, M, D_, D_);
  gemm_bt<f16, 0><<<dim3(DKV_ / 128, M / 128), 256, 0, stream>>>(xh, wkh, bk, kh, M, DKV_, D_);
  gemm_bt<f16, 1><<<dim3(DKV_ / 128, M / 128), 256, 0, stream>>>(xh, wvh, bv, v4h, M, DKV_, D_);

  attn_kernel<<<dim3(1024), 256, 0, stream>>>(qh, kh, v4h, ah);

  gemm_bt<float, 0><<<dim3(D_ / 128, M / 128), 256, 0, stream>>>(ah, woh, bo, out, M, D_, D_);
}

// Round 4
// 295.827 us; speedup vs baseline: 2.5202x; 1.9023x over previous
//
#include <hip/hip_runtime.h>
#include <hip/hip_bf16.h>
#include <cmath>
#include <stdint.h>

#define B_ 2
#define S_ 2048
#define D_ 2048
#define H_ 16
#define HKV_ 2
#define DH_ 128
#define G_ 8
#define DKV_ 256   // HKV*DH
#define MROWS_ (B_ * S_)   // 4096

typedef _Float16 f16;
typedef _Float16 f16x8 __attribute__((ext_vector_type(8)));
typedef _Float16 f16x4 __attribute__((ext_vector_type(4)));
typedef float f32x4 __attribute__((ext_vector_type(4)));

__device__ __forceinline__ void gload_lds16(const void* g, void* lds) {
  __builtin_amdgcn_global_load_lds((const __attribute__((address_space(1))) void*)g,
                                   (__attribute__((address_space(3))) void*)lds,
                                   16, 0, 0);
}

__global__ void cast_kernel(const float* __restrict__ in, f16* __restrict__ out, int n4) {
  int i = blockIdx.x * blockDim.x + threadIdx.x;
  int stride = gridDim.x * blockDim.x;
  for (; i < n4; i += stride) {
    float4 v = reinterpret_cast<const float4*>(in)[i];
    f16x4 o = { (f16)v.x, (f16)v.y, (f16)v.z, (f16)v.w };
    reinterpret_cast<f16x4*>(out)[i] = o;
  }
}

// C[m][n] = sum_k A[m][k] * Bm[n][k] + bias[n]
// A: (M,K) f16 row-major, Bm: (N,K) f16 row-major.  M%128==0, N%128==0, K%64==0.
// MODE 0: row-major OUT_T.  MODE 1: kv-interleaved transpose for attention V:
//   element C[m][n] stored at C4[(m>>2)*(N*4) + n*4 + (m&3)]  (f16).
template<typename OUT_T, int MODE>
__global__ __launch_bounds__(256)
void gemm_bt(const f16* __restrict__ A, const f16* __restrict__ Bm,
             const float* __restrict__ bias, OUT_T* __restrict__ C,
             int M, int N, int K) {
  __shared__ __align__(16) f16 sA[128 * 64];
  __shared__ __align__(16) f16 sB[128 * 64];
  const int tid  = threadIdx.x;
  const int lane = tid & 63;
  const int w    = tid >> 6;        // wave 0..3
  const int wr   = w >> 1, wc = w & 1;
  const int r16  = lane & 15, grp = lane >> 4;
  const int bm = blockIdx.y * 128;
  const int bn = blockIdx.x * 128;

  f32x4 acc[4][4] = {};

  for (int k0 = 0; k0 < K; k0 += 64) {
#pragma unroll
    for (int j = 0; j < 4; ++j) {
      int seg = j * 4 + w;
      int e = seg * 512 + lane * 8;
      int r = e >> 6, c = e & 63;
      gload_lds16(A  + (size_t)(bm + r) * K + k0 + c, &sA[seg * 512]);
      gload_lds16(Bm + (size_t)(bn + r) * K + k0 + c, &sB[seg * 512]);
    }
    asm volatile("s_waitcnt vmcnt(0)" ::: "memory");
    __syncthreads();

#pragma unroll
    for (int kk = 0; kk < 64; kk += 32) {
      f16x8 af[4], bf[4];
#pragma unroll
      for (int m = 0; m < 4; ++m)
        af[m] = *reinterpret_cast<const f16x8*>(&sA[(wr * 64 + m * 16 + r16) * 64 + kk + grp * 8]);
#pragma unroll
      for (int n = 0; n < 4; ++n)
        bf[n] = *reinterpret_cast<const f16x8*>(&sB[(wc * 64 + n * 16 + r16) * 64 + kk + grp * 8]);
#pragma unroll
      for (int m = 0; m < 4; ++m)
#pragma unroll
        for (int n = 0; n < 4; ++n)
          acc[m][n] = __builtin_amdgcn_mfma_f32_16x16x32_f16(af[m], bf[n], acc[m][n], 0, 0, 0);
    }
    __syncthreads();
  }

  // epilogue: per 16x16 frag: col = lane&15, row = grp*4 + j
#pragma unroll
  for (int n = 0; n < 4; ++n) {
    int col = bn + wc * 64 + n * 16 + r16;
    float bv = bias ? bias[col] : 0.f;
#pragma unroll
    for (int m = 0; m < 4; ++m) {
      int row0 = bm + wr * 64 + m * 16 + grp * 4;   // 4-aligned
      if constexpr (MODE == 1) {
        f16x4 st;
#pragma unroll
        for (int j = 0; j < 4; ++j) st[j] = (f16)(acc[m][n][j] + bv);
        *reinterpret_cast<f16x4*>(&C[(size_t)(row0 >> 2) * (N * 4) + col * 4]) = st;
      } else {
#pragma unroll
        for (int j = 0; j < 4; ++j) {
          float v = acc[m][n][j] + bv;
          C[(size_t)(row0 + j) * N + col] = (OUT_T)v;
        }
      }
    }
  }
}

// Flash attention, causal, GQA.
// Block = 256 threads (4 waves = 4 q-heads of one kv-head). Block processes
// two q-tiles (qt=j, then qt=127-j) sequentially -> all 512 blocks have exactly
// 65 kv-32 iterations (uniform). K,V staged in double-buffered swizzled LDS.
// Q,K row-major f16; V4 kv-interleaved: V[s][d] at V4[(s>>2)*1024 + d*4 + (s&3)].
__global__ __launch_bounds__(256)
void attn_kernel(const f16* __restrict__ Q, const f16* __restrict__ K,
                 const f16* __restrict__ V4, f16* __restrict__ O) {
  __shared__ __align__(16) f16 sK[2][4096];   // [buf][32 rows x 128], XOR-swizzled 16B chunks
  __shared__ __align__(16) f16 sV[2][4096];   // [buf][8 grp x 512], XOR-swizzled 16B chunks

  const int tid  = threadIdx.x;
  const int lane = tid & 63;
  const int w    = tid >> 6;           // wave 0..3
  const int qi   = lane & 15, grp = lane >> 4;
  const int bid  = blockIdx.x;
  const int j    = bid & 63;
  const int hh   = (bid >> 6) & 1;
  const int kvh  = (bid >> 7) & 1;
  const int b    = bid >> 8;
  const int hq   = kvh * 8 + hh * 4 + w;
  const f16 SCL  = (f16)0.08838834764831845f;  // 1/sqrt(128)

  const f16* Kb = K  + (size_t)b * S_ * DKV_ + kvh * DH_;          // + row*DKV + col
  const f16* Vb = V4 + (size_t)b * S_ * DKV_ + kvh * 512;          // + sg*1024 + dl*4 + (s&3)

  // staging: thread covers chunks tid and tid+256 of each 512-chunk (8KB) tile
  auto stage = [&](int t32, int buf) {
#pragma unroll
    for (int p2 = 0; p2 < 2; ++p2) {
      int ci = p2 * 256 + tid;
      // K chunk: row r, stored chunk cs holds source col cs ^ (r&7)
      int r = ci >> 4, cs = ci & 15;
      gload_lds16(Kb + (size_t)(t32 * 32 + r) * DKV_ + (cs ^ (r & 7)) * 8,
                  (char*)&sK[buf][0] + p2 * 4096 + w * 1024);
      // V chunk: group g (4 kv rows), stored chunk cc holds source chunk cc ^ g
      int g = ci >> 6, cc = ci & 63;
      gload_lds16(Vb + (size_t)(t32 * 8 + g) * 1024 + ((cc ^ g) * 8),
                  (char*)&sV[buf][0] + p2 * 4096 + w * 1024);
    }
  };

  for (int task = 0; task < 2; ++task) {
    const int qt = task ? (127 - j) : j;
    const int n32 = (qt >> 1) + 1;
    const int q_pos = qt * 16 + qi;

    // Q fragments (B-operand of swapped QK^T), pre-scaled by 1/sqrt(DH)
    const size_t qbase = ((size_t)(b * S_ + qt * 16 + qi)) * D_ + hq * DH_;
    f16x8 qf[4];
#pragma unroll
    for (int kd = 0; kd < 4; ++kd) {
      qf[kd] = *reinterpret_cast<const f16x8*>(Q + qbase + kd * 32 + grp * 8);
#pragma unroll
      for (int e = 0; e < 8; ++e) qf[kd][e] *= SCL;
    }

    float m = -INFINITY, lsum = 0.f;
    f32x4 accO[8] = {};

    // prologue: stage tile 0
    stage(0, 0);
    asm volatile("s_waitcnt vmcnt(0)" ::: "memory");
    __syncthreads();

    for (int t = 0; t < n32; ++t) {
      const int buf = t & 1;
      if (t + 1 < n32) stage(t + 1, buf ^ 1);

      const int kv0 = t * 32;
      // ---- QK^T (swapped): s{0,1}[jj] = S^T[kv0+half*16+grp*4+jj][q=qi]
      f32x4 s0 = {}, s1 = {};
#pragma unroll
      for (int kd = 0; kd < 4; ++kd) {
        const int cc = kd * 4 + grp;
        f16x8 k0 = *reinterpret_cast<const f16x8*>(&sK[buf][qi * 128 + ((cc ^ (qi & 7)) << 3)]);
        f16x8 k1 = *reinterpret_cast<const f16x8*>(&sK[buf][(16 + qi) * 128 + ((cc ^ (qi & 7)) << 3)]);
        s0 = __builtin_amdgcn_mfma_f32_16x16x32_f16(k0, qf[kd], s0, 0, 0, 0);
        s1 = __builtin_amdgcn_mfma_f32_16x16x32_f16(k1, qf[kd], s1, 0, 0, 0);
      }
      // ---- causal mask (branchless, exact only needed on last tile but cheap)
      float p[8], tm = -INFINITY;
#pragma unroll
      for (int jj = 0; jj < 4; ++jj) {
        int kvp0 = kv0 + grp * 4 + jj;
        p[jj]     = (kvp0 > q_pos)      ? -INFINITY : s0[jj];
        p[4 + jj] = (kvp0 + 16 > q_pos) ? -INFINITY : s1[jj];
      }
#pragma unroll
      for (int i = 0; i < 8; ++i) tm = fmaxf(tm, p[i]);
      tm = fmaxf(tm, __shfl_xor(tm, 16));
      tm = fmaxf(tm, __shfl_xor(tm, 32));
      float m_new = fmaxf(m, tm);
      float scale = __expf(m - m_new);
      m = m_new;
      float ps = 0.f;
#pragma unroll
      for (int i = 0; i < 8; ++i) {
        p[i] = __expf(p[i] - m);
        ps += p[i];
      }
      lsum = lsum * scale + ps;          // per-lane partial; reduced at end

      f16x4 pf0 = { (f16)p[0], (f16)p[1], (f16)p[2], (f16)p[3] };
      f16x4 pf1 = { (f16)p[4], (f16)p[5], (f16)p[6], (f16)p[7] };
      // ---- PV
#pragma unroll
      for (int dt = 0; dt < 8; ++dt) {
        const int dl = dt * 16 + qi;
        const int c  = dl >> 1;
        f16x4 v0 = *reinterpret_cast<const f16x4*>(
            &sV[buf][grp * 512 + ((c ^ grp) << 3) + (dl & 1) * 4]);
        f16x4 v1 = *reinterpret_cast<const f16x4*>(
            &sV[buf][(grp + 4) * 512 + ((c ^ (grp + 4)) << 3) + (dl & 1) * 4]);
#pragma unroll
        for (int jj = 0; jj < 4; ++jj) accO[dt][jj] *= scale;
        accO[dt] = __builtin_amdgcn_mfma_f32_16x16x16f16(v0, pf0, accO[dt], 0, 0, 0);
        accO[dt] = __builtin_amdgcn_mfma_f32_16x16x16f16(v1, pf1, accO[dt], 0, 0, 0);
      }

      asm volatile("s_waitcnt vmcnt(0)" ::: "memory");
      __syncthreads();
    }

    // epilogue: reduce lsum across grp, normalize, store
    lsum += __shfl_xor(lsum, 16);
    lsum += __shfl_xor(lsum, 32);
    float inv_l = 1.f / lsum;
    const size_t obase = ((size_t)(b * S_ + qt * 16 + qi)) * D_ + hq * DH_;
#pragma unroll
    for (int dt = 0; dt < 8; ++dt) {
      f16x4 st;
#pragma unroll
      for (int jj = 0; jj < 4; ++jj) st[jj] = (f16)(accO[dt][jj] * inv_l);
      *reinterpret_cast<f16x4*>(&O[obase + dt * 16 + grp * 4]) = st;
    }
    __syncthreads();   // buf0 of next task must not be staged before all waves done
  }
}

extern "C" void kernel_launch(void* const* d_in, const int* in_sizes, int n_in,
                              void* d_out, int out_size, void* d_ws, size_t ws_size,
                              hipStream_t stream) {
  const float* x  = (const float*)d_in[0];
  const float* Wq = (const float*)d_in[1];
  const float* bq = (const float*)d_in[2];
  const float* Wk = (const float*)d_in[3];
  const float* bk = (const float*)d_in[4];
  const float* Wv = (const float*)d_in[5];
  const float* bv = (const float*)d_in[6];
  const float* Wo = (const float*)d_in[7];
  const float* bo = (const float*)d_in[8];
  float* out = (float*)d_out;

  char* ws = (char*)d_ws;
  size_t off = 0;
  auto alloc = [&](size_t bytes) {
    char* p = ws + off;
    off += (bytes + 255) & ~(size_t)255;
    return p;
  };
  f16* xh  = (f16*)alloc((size_t)B_ * S_ * D_ * 2);
  f16* wqh = (f16*)alloc((size_t)D_ * D_ * 2);
  f16* wkh = (f16*)alloc((size_t)DKV_ * D_ * 2);
  f16* wvh = (f16*)alloc((size_t)DKV_ * D_ * 2);
  f16* woh = (f16*)alloc((size_t)D_ * D_ * 2);
  f16* qh  = (f16*)alloc((size_t)B_ * S_ * D_ * 2);
  f16* kh  = (f16*)alloc((size_t)B_ * S_ * DKV_ * 2);
  f16* v4h = (f16*)alloc((size_t)B_ * S_ * DKV_ * 2);   // kv-interleaved V^T
  f16* ah  = (f16*)alloc((size_t)B_ * S_ * D_ * 2);

  auto cast = [&](const float* in, f16* o, int n) {
    int n4 = n / 4;
    int grid = (n4 + 255) / 256;
    if (grid > 2048) grid = 2048;
    cast_kernel<<<dim3(grid), dim3(256), 0, stream>>>(in, o, n4);
  };
  cast(x,  xh,  B_ * S_ * D_);
  cast(Wq, wqh, D_ * D_);
  cast(Wk, wkh, DKV_ * D_);
  cast(Wv, wvh, DKV_ * D_);
  cast(Wo, woh, D_ * D_);

  const int M = B_ * S_;
  gemm_bt<f16, 0><<<dim3(D_ / 128, M / 128), 256, 0, stream>>>(xh, wqh, bq, qh, M, D_, D_);
  gemm_bt<f16, 0><<<dim3(DKV_ / 128, M / 128), 256, 0, stream>>>(xh, wkh, bk, kh, M, DKV_, D_);
  gemm_bt<f16, 1><<<dim3(DKV_ / 128, M / 128), 256, 0, stream>>>(xh, wvh, bv, v4h, M, DKV_, D_);

  attn_kernel<<<dim3(512), 256, 0, stream>>>(qh, kh, v4h, ah);

  gemm_bt<float, 0><<<dim3(D_ / 128, M / 128), 256, 0, stream>>>(ah, woh, bo, out, M, D_, D_);
}

// Round 6
// 266.029 us; speedup vs baseline: 2.8025x; 1.1120x over previous
//
#include <hip/hip_runtime.h>
#include <hip/hip_bf16.h>
#include <cmath>
#include <stdint.h>

#define B_ 2
#define S_ 2048
#define D_ 2048
#define H_ 16
#define HKV_ 2
#define DH_ 128
#define G_ 8
#define DKV_ 256   // HKV*DH
#define NQKV_ 2560 // D_ + 2*DKV

typedef _Float16 f16;
typedef _Float16 f16x8 __attribute__((ext_vector_type(8)));
typedef _Float16 f16x4 __attribute__((ext_vector_type(4)));
typedef float f32x4 __attribute__((ext_vector_type(4)));

__device__ __forceinline__ void gload_lds16(const void* g, void* lds) {
  __builtin_amdgcn_global_load_lds((const __attribute__((address_space(1))) void*)g,
                                   (__attribute__((address_space(3))) void*)lds,
                                   16, 0, 0);
}

__global__ void cast_kernel(const float* __restrict__ in, f16* __restrict__ out, int n4) {
  int i = blockIdx.x * blockDim.x + threadIdx.x;
  int stride = gridDim.x * blockDim.x;
  for (; i < n4; i += stride) {
    float4 v = reinterpret_cast<const float4*>(in)[i];
    f16x4 o = { (f16)v.x, (f16)v.y, (f16)v.z, (f16)v.w };
    reinterpret_cast<f16x4*>(out)[i] = o;
  }
}

// C[m][n] = sum_k A[m][k]*Bm[n][k] + bias[n].  1-D grid (nwg % 8 == 0), XCD-swizzled.
// EPI 0: float row-major to oF (width N).
// EPI 1: fused QKV routing: col<2048 -> oQ row-major 2048; col<2304 -> oK row-major 256;
//        else -> oV kv-interleaved: V[s][d] at oV[(s>>2)*1024 + d*4 + (s&3)], d=col-2304.
template<int EPI>
__global__ __launch_bounds__(256)
void gemm_core(const f16* __restrict__ A, const f16* __restrict__ Bm,
               const float* __restrict__ bias,
               f16* __restrict__ oQ, f16* __restrict__ oK, f16* __restrict__ oV,
               float* __restrict__ oF,
               int M, int N, int K, int nbx) {
  __shared__ __align__(16) f16 sA[128 * 64];
  __shared__ __align__(16) f16 sB[128 * 64];
  const int tid  = threadIdx.x;
  const int lane = tid & 63;
  const int w    = tid >> 6;
  const int wr   = w >> 1, wc = w & 1;
  const int r16  = lane & 15, grp = lane >> 4;
  const int nwg  = gridDim.x;
  const int cpx  = nwg >> 3;
  const int lg   = (blockIdx.x & 7) * cpx + (blockIdx.x >> 3);  // bijective XCD swizzle
  const int bm   = (lg / nbx) * 128;
  const int bn   = (lg % nbx) * 128;

  f32x4 acc[4][4] = {};

  for (int k0 = 0; k0 < K; k0 += 64) {
#pragma unroll
    for (int j = 0; j < 4; ++j) {
      int seg = j * 4 + w;
      int e = seg * 512 + lane * 8;
      int r = e >> 6, c = e & 63;
      gload_lds16(A  + (size_t)(bm + r) * K + k0 + c, &sA[seg * 512]);
      gload_lds16(Bm + (size_t)(bn + r) * K + k0 + c, &sB[seg * 512]);
    }
    asm volatile("s_waitcnt vmcnt(0)" ::: "memory");
    __syncthreads();

#pragma unroll
    for (int kk = 0; kk < 64; kk += 32) {
      f16x8 af[4], bf[4];
#pragma unroll
      for (int m = 0; m < 4; ++m)
        af[m] = *reinterpret_cast<const f16x8*>(&sA[(wr * 64 + m * 16 + r16) * 64 + kk + grp * 8]);
#pragma unroll
      for (int n = 0; n < 4; ++n)
        bf[n] = *reinterpret_cast<const f16x8*>(&sB[(wc * 64 + n * 16 + r16) * 64 + kk + grp * 8]);
#pragma unroll
      for (int m = 0; m < 4; ++m)
#pragma unroll
        for (int n = 0; n < 4; ++n)
          acc[m][n] = __builtin_amdgcn_mfma_f32_16x16x32_f16(af[m], bf[n], acc[m][n], 0, 0, 0);
    }
    __syncthreads();
  }

#pragma unroll
  for (int n = 0; n < 4; ++n) {
    int col = bn + wc * 64 + n * 16 + r16;
    float bv = bias ? bias[col] : 0.f;
#pragma unroll
    for (int m = 0; m < 4; ++m) {
      int row0 = bm + wr * 64 + m * 16 + grp * 4;   // 4-aligned
      if constexpr (EPI == 0) {
#pragma unroll
        for (int j = 0; j < 4; ++j)
          oF[(size_t)(row0 + j) * N + col] = acc[m][n][j] + bv;
      } else {
        if (bn < 2048) {
#pragma unroll
          for (int j = 0; j < 4; ++j)
            oQ[(size_t)(row0 + j) * 2048 + col] = (f16)(acc[m][n][j] + bv);
        } else if (bn < 2304) {
#pragma unroll
          for (int j = 0; j < 4; ++j)
            oK[(size_t)(row0 + j) * 256 + (col - 2048)] = (f16)(acc[m][n][j] + bv);
        } else {
          f16x4 st;
#pragma unroll
          for (int j = 0; j < 4; ++j) st[j] = (f16)(acc[m][n][j] + bv);
          *reinterpret_cast<f16x4*>(&oV[(size_t)(row0 >> 2) * 1024 + (col - 2304) * 4]) = st;
        }
      }
    }
  }
}

// Flash attention, causal, GQA.  Block = 4 waves = 4 q-heads of one kv-head;
// two uniform tasks (qt=j, 127-j) -> 65 kv-32 iters per block.  4-buffer LDS,
// depth-2 prefetch with counted vmcnt (never 0 in main loop), raw s_barrier.
__global__ __launch_bounds__(256)
void attn_kernel(const f16* __restrict__ Q, const f16* __restrict__ K,
                 const f16* __restrict__ V4, f16* __restrict__ O) {
  __shared__ __align__(16) f16 sK[4][4096];
  __shared__ __align__(16) f16 sV[4][4096];

  const int tid  = threadIdx.x;
  const int lane = tid & 63;
  const int w    = tid >> 6;
  const int qi   = lane & 15, grp = lane >> 4;
  const int bid  = blockIdx.x;
  const int lg   = (bid & 7) * 64 + (bid >> 3);  // group (b,kvh,hh) per XCD
  const int j    = lg & 63;
  const int hh   = (lg >> 6) & 1;
  const int kvh  = (lg >> 7) & 1;
  const int b    = lg >> 8;
  const int hq   = kvh * 8 + hh * 4 + w;
  const f16 SCL2 = (f16)(0.08838834764831845f * 1.44269504088896f);  // 1/sqrt(128)*log2(e)

  const f16* Kb = K  + (size_t)b * S_ * DKV_ + kvh * DH_;
  const f16* Vb = V4 + (size_t)b * S_ * DKV_ + kvh * 512;

  auto stage = [&](int t32, int buf) {   // exactly 4 vm loads per thread
#pragma unroll
    for (int p2 = 0; p2 < 2; ++p2) {
      int ci = p2 * 256 + tid;
      int r = ci >> 4, cs = ci & 15;
      gload_lds16(Kb + (size_t)(t32 * 32 + r) * DKV_ + ((cs ^ (r & 7)) * 8),
                  (char*)&sK[buf][0] + p2 * 4096 + w * 1024);
      int g = ci >> 6, cc = ci & 63;
      gload_lds16(Vb + (size_t)(t32 * 8 + g) * 1024 + ((cc ^ g) * 8),
                  (char*)&sV[buf][0] + p2 * 4096 + w * 1024);
    }
  };

  for (int task = 0; task < 2; ++task) {
    const int qt  = task ? (127 - j) : j;
    const int n32 = (qt >> 1) + 1;
    const int q_pos = qt * 16 + qi;

    const size_t qbase = ((size_t)(b * S_ + qt * 16 + qi)) * D_ + hq * DH_;
    f16x8 qf[4];
#pragma unroll
    for (int kd = 0; kd < 4; ++kd) {
      qf[kd] = *reinterpret_cast<const f16x8*>(Q + qbase + kd * 32 + grp * 8);
#pragma unroll
      for (int e = 0; e < 8; ++e) qf[kd][e] *= SCL2;
    }

    float m = -INFINITY, lsum = 0.f;
    f32x4 accO[8] = {};

    stage(0, 0);
    stage(1, 1);
    asm volatile("s_waitcnt vmcnt(4)" ::: "memory");   // tile0 landed
    __builtin_amdgcn_s_barrier();

    for (int t = 0; t < n32; ++t) {
      const int buf = t & 3;
      const bool more = (t + 2 < n32);
      if (more) stage(t + 2, (t + 2) & 3);

      const int kv0 = t * 32;
      const f16* sKb = &sK[buf][0];
      const f16* sVb = &sV[buf][0];

      // QK^T (swapped): s{0,1}[jj] = S^T[kv0+half*16+grp*4+jj][q=qi], log2 units
      f32x4 s0 = {}, s1 = {};
#pragma unroll
      for (int kd = 0; kd < 4; ++kd) {
        const int cx = ((kd * 4 + grp) ^ (qi & 7)) << 3;
        f16x8 k0 = *reinterpret_cast<const f16x8*>(sKb + qi * 128 + cx);
        f16x8 k1 = *reinterpret_cast<const f16x8*>(sKb + (16 + qi) * 128 + cx);
        s0 = __builtin_amdgcn_mfma_f32_16x16x32_f16(k0, qf[kd], s0, 0, 0, 0);
        s1 = __builtin_amdgcn_mfma_f32_16x16x32_f16(k1, qf[kd], s1, 0, 0, 0);
      }
      float p[8];
#pragma unroll
      for (int jj = 0; jj < 4; ++jj) { p[jj] = s0[jj]; p[4 + jj] = s1[jj]; }
      if (t == n32 - 1) {              // only the last tile can cross the diagonal
#pragma unroll
        for (int jj = 0; jj < 4; ++jj) {
          int kvp = kv0 + grp * 4 + jj;
          p[jj]     = (kvp > q_pos)      ? -INFINITY : p[jj];
          p[4 + jj] = (kvp + 16 > q_pos) ? -INFINITY : p[4 + jj];
        }
      }
      float tm = -INFINITY;
#pragma unroll
      for (int i = 0; i < 8; ++i) tm = fmaxf(tm, p[i]);
      tm = fmaxf(tm, __shfl_xor(tm, 16));
      tm = fmaxf(tm, __shfl_xor(tm, 32));
      if (!__all(tm <= m + 8.f)) {     // defer-max: rescale only on real growth
        float mn = fmaxf(m, tm);
        float sc = exp2f(m - mn);
        m = mn;
        lsum *= sc;
#pragma unroll
        for (int dt = 0; dt < 8; ++dt)
#pragma unroll
          for (int jj = 0; jj < 4; ++jj) accO[dt][jj] *= sc;
      }
      float ps = 0.f;
#pragma unroll
      for (int i = 0; i < 8; ++i) {
        p[i] = exp2f(p[i] - m);
        ps += p[i];
      }
      lsum += ps;                      // per-lane partial, reduced at task end

      f16x4 pf0 = { (f16)p[0], (f16)p[1], (f16)p[2], (f16)p[3] };
      f16x4 pf1 = { (f16)p[4], (f16)p[5], (f16)p[6], (f16)p[7] };
#pragma unroll
      for (int dt = 0; dt < 8; ++dt) {
        const int dl = dt * 16 + qi;
        const int c  = dl >> 1;
        f16x4 v0 = *reinterpret_cast<const f16x4*>(
            sVb + grp * 512 + ((c ^ grp) << 3) + (dl & 1) * 4);
        f16x4 v1 = *reinterpret_cast<const f16x4*>(
            sVb + (grp + 4) * 512 + ((c ^ (grp + 4)) << 3) + (dl & 1) * 4);
        accO[dt] = __builtin_amdgcn_mfma_f32_16x16x16f16(v0, pf0, accO[dt], 0, 0, 0);
        accO[dt] = __builtin_amdgcn_mfma_f32_16x16x16f16(v1, pf1, accO[dt], 0, 0, 0);
      }

      if (more) { asm volatile("s_waitcnt vmcnt(4)" ::: "memory"); }  // tile t+1 landed
      else      { asm volatile("s_waitcnt vmcnt(0)" ::: "memory"); }
      __builtin_amdgcn_s_barrier();
    }

    lsum += __shfl_xor(lsum, 16);
    lsum += __shfl_xor(lsum, 32);
    float inv_l = 1.f / lsum;
    const size_t obase = ((size_t)(b * S_ + qt * 16 + qi)) * D_ + hq * DH_;
#pragma unroll
    for (int dt = 0; dt < 8; ++dt) {
      f16x4 st;
#pragma unroll
      for (int jj = 0; jj < 4; ++jj) st[jj] = (f16)(accO[dt][jj] * inv_l);
      *reinterpret_cast<f16x4*>(&O[obase + dt * 16 + grp * 4]) = st;
    }
  }
}

extern "C" void kernel_launch(void* const* d_in, const int* in_sizes, int n_in,
                              void* d_out, int out_size, void* d_ws, size_t ws_size,
                              hipStream_t stream) {
  const float* x  = (const float*)d_in[0];
  const float* Wq = (const float*)d_in[1];
  const float* bq = (const float*)d_in[2];
  const float* Wk = (const float*)d_in[3];
  const float* bk = (const float*)d_in[4];
  const float* Wv = (const float*)d_in[5];
  const float* bv = (const float*)d_in[6];
  const float* Wo = (const float*)d_in[7];
  const float* bo = (const float*)d_in[8];
  float* out = (float*)d_out;

  char* ws = (char*)d_ws;
  size_t off = 0;
  auto alloc = [&](size_t bytes) {
    char* p = ws + off;
    off += (bytes + 255) & ~(size_t)255;
    return p;
  };
  f16*   xh    = (f16*)alloc((size_t)B_ * S_ * D_ * 2);
  f16*   wqkv  = (f16*)alloc((size_t)NQKV_ * D_ * 2);
  f16*   woh   = (f16*)alloc((size_t)D_ * D_ * 2);
  f16*   qh    = (f16*)alloc((size_t)B_ * S_ * D_ * 2);
  f16*   kh    = (f16*)alloc((size_t)B_ * S_ * DKV_ * 2);
  f16*   v4h   = (f16*)alloc((size_t)B_ * S_ * DKV_ * 2);
  f16*   ah    = (f16*)alloc((size_t)B_ * S_ * D_ * 2);
  float* bqkv  = (float*)alloc((size_t)NQKV_ * 4);

  auto cast = [&](const float* in, f16* o, int n) {
    int n4 = n / 4;
    int grid = (n4 + 255) / 256;
    if (grid > 2048) grid = 2048;
    cast_kernel<<<dim3(grid), dim3(256), 0, stream>>>(in, o, n4);
  };
  cast(x,  xh, B_ * S_ * D_);
  cast(Wq, wqkv,                               D_ * D_);
  cast(Wk, wqkv + (size_t)D_ * D_,             DKV_ * D_);
  cast(Wv, wqkv + (size_t)(D_ + DKV_) * D_,    DKV_ * D_);
  cast(Wo, woh, D_ * D_);
  (void)hipMemcpyAsync(bqkv,             bq, D_ * 4,   hipMemcpyDeviceToDevice, stream);
  (void)hipMemcpyAsync(bqkv + D_,        bk, DKV_ * 4, hipMemcpyDeviceToDevice, stream);
  (void)hipMemcpyAsync(bqkv + D_ + DKV_, bv, DKV_ * 4, hipMemcpyDeviceToDevice, stream);

  const int M = B_ * S_;
  gemm_core<1><<<dim3((M / 128) * (NQKV_ / 128)), 256, 0, stream>>>(
      xh, wqkv, bqkv, qh, kh, v4h, nullptr, M, NQKV_, D_, NQKV_ / 128);

  attn_kernel<<<dim3(512), 256, 0, stream>>>(qh, kh, v4h, ah);

  gemm_core<0><<<dim3((M / 128) * (D_ / 128)), 256, 0, stream>>>(
      ah, woh, bo, nullptr, nullptr, nullptr, out, M, D_, D_, D_ / 128);
}

// Round 7
// 248.736 us; speedup vs baseline: 2.9974x; 1.0695x over previous
//
#include <hip/hip_runtime.h>
#include <hip/hip_bf16.h>
#include <cmath>
#include <stdint.h>

#define B_ 2
#define S_ 2048
#define D_ 2048
#define H_ 16
#define HKV_ 2
#define DH_ 128
#define G_ 8
#define DKV_ 256   // HKV*DH
#define NQKV_ 2560 // D_ + 2*DKV

typedef _Float16 f16;
typedef _Float16 f16x8 __attribute__((ext_vector_type(8)));
typedef _Float16 f16x4 __attribute__((ext_vector_type(4)));
typedef float f32x4 __attribute__((ext_vector_type(4)));

__device__ __forceinline__ void gload_lds16(const void* g, void* lds) {
  __builtin_amdgcn_global_load_lds((const __attribute__((address_space(1))) void*)g,
                                   (__attribute__((address_space(3))) void*)lds,
                                   16, 0, 0);
}

__global__ void cast_kernel(const float* __restrict__ in, f16* __restrict__ out, int n4) {
  int i = blockIdx.x * blockDim.x + threadIdx.x;
  int stride = gridDim.x * blockDim.x;
  for (; i < n4; i += stride) {
    float4 v = reinterpret_cast<const float4*>(in)[i];
    f16x4 o = { (f16)v.x, (f16)v.y, (f16)v.z, (f16)v.w };
    reinterpret_cast<f16x4*>(out)[i] = o;
  }
}

// C[m][n] = sum_k A[m][k]*Bm[n][k] + bias[n].  1-D grid (nwg % 8 == 0), XCD-swizzled.
// Double-buffered LDS, stage(t+1) overlaps compute(t), counted drain only at loop end.
// EPI 0: float row-major to oF (width N).
// EPI 1: fused QKV routing: col<2048 -> oQ row-major 2048; col<2304 -> oK row-major 256;
//        else -> oV kv-interleaved: V[s][d] at oV[(s>>2)*1024 + d*4 + (s&3)], d=col-2304.
template<int EPI>
__global__ __launch_bounds__(256)
void gemm_core(const f16* __restrict__ A, const f16* __restrict__ Bm,
               const float* __restrict__ bias,
               f16* __restrict__ oQ, f16* __restrict__ oK, f16* __restrict__ oV,
               float* __restrict__ oF,
               int M, int N, int K, int nbx) {
  __shared__ __align__(16) f16 sA[2][128 * 64];
  __shared__ __align__(16) f16 sB[2][128 * 64];
  const int tid  = threadIdx.x;
  const int lane = tid & 63;
  const int w    = tid >> 6;
  const int wr   = w >> 1, wc = w & 1;
  const int r16  = lane & 15, grp = lane >> 4;
  const int nwg  = gridDim.x;
  const int cpx  = nwg >> 3;
  const int lg   = (blockIdx.x & 7) * cpx + (blockIdx.x >> 3);  // bijective XCD swizzle
  const int bm   = (lg / nbx) * 128;
  const int bn   = (lg % nbx) * 128;

  f32x4 acc[4][4] = {};

  auto stage = [&](int k0, int buf) {   // 8 gload_lds per thread
#pragma unroll
    for (int j = 0; j < 4; ++j) {
      int seg = j * 4 + w;
      int e = seg * 512 + lane * 8;
      int r = e >> 6, c = e & 63;
      gload_lds16(A  + (size_t)(bm + r) * K + k0 + c, &sA[buf][seg * 512]);
      gload_lds16(Bm + (size_t)(bn + r) * K + k0 + c, &sB[buf][seg * 512]);
    }
  };

  stage(0, 0);
  asm volatile("s_waitcnt vmcnt(0)" ::: "memory");
  __builtin_amdgcn_s_barrier();

  const int nk = K >> 6;
  for (int t = 0; t < nk; ++t) {
    const int buf = t & 1;
    if (t + 1 < nk) stage((t + 1) << 6, buf ^ 1);

#pragma unroll
    for (int kk = 0; kk < 64; kk += 32) {
      f16x8 af[4], bf[4];
#pragma unroll
      for (int m = 0; m < 4; ++m)
        af[m] = *reinterpret_cast<const f16x8*>(&sA[buf][(wr * 64 + m * 16 + r16) * 64 + kk + grp * 8]);
#pragma unroll
      for (int n = 0; n < 4; ++n)
        bf[n] = *reinterpret_cast<const f16x8*>(&sB[buf][(wc * 64 + n * 16 + r16) * 64 + kk + grp * 8]);
#pragma unroll
      for (int m = 0; m < 4; ++m)
#pragma unroll
        for (int n = 0; n < 4; ++n)
          acc[m][n] = __builtin_amdgcn_mfma_f32_16x16x32_f16(af[m], bf[n], acc[m][n], 0, 0, 0);
    }

    asm volatile("s_waitcnt vmcnt(0)" ::: "memory");  // next tile landed (overlapped compute)
    __builtin_amdgcn_s_barrier();
  }

#pragma unroll
  for (int n = 0; n < 4; ++n) {
    int col = bn + wc * 64 + n * 16 + r16;
    float bv = bias ? bias[col] : 0.f;
#pragma unroll
    for (int m = 0; m < 4; ++m) {
      int row0 = bm + wr * 64 + m * 16 + grp * 4;   // 4-aligned
      if constexpr (EPI == 0) {
#pragma unroll
        for (int j = 0; j < 4; ++j)
          oF[(size_t)(row0 + j) * N + col] = acc[m][n][j] + bv;
      } else {
        if (bn < 2048) {
#pragma unroll
          for (int j = 0; j < 4; ++j)
            oQ[(size_t)(row0 + j) * 2048 + col] = (f16)(acc[m][n][j] + bv);
        } else if (bn < 2304) {
#pragma unroll
          for (int j = 0; j < 4; ++j)
            oK[(size_t)(row0 + j) * 256 + (col - 2048)] = (f16)(acc[m][n][j] + bv);
        } else {
          f16x4 st;
#pragma unroll
          for (int j = 0; j < 4; ++j) st[j] = (f16)(acc[m][n][j] + bv);
          *reinterpret_cast<f16x4*>(&oV[(size_t)(row0 >> 2) * 1024 + (col - 2304) * 4]) = st;
        }
      }
    }
  }
}

// Flash attention, causal, GQA.  Block = 4 waves = 4 q-heads of one kv-head;
// two uniform tasks (qt=j, 127-j) -> 65 kv-32 iters per block.  4-buffer LDS,
// depth-2 prefetch with counted vmcnt (never 0 in main loop), raw s_barrier.
__global__ __launch_bounds__(256)
void attn_kernel(const f16* __restrict__ Q, const f16* __restrict__ K,
                 const f16* __restrict__ V4, f16* __restrict__ O) {
  __shared__ __align__(16) f16 sK[4][4096];
  __shared__ __align__(16) f16 sV[4][4096];

  const int tid  = threadIdx.x;
  const int lane = tid & 63;
  const int w    = tid >> 6;
  const int qi   = lane & 15, grp = lane >> 4;
  const int bid  = blockIdx.x;
  const int lg   = (bid & 7) * 64 + (bid >> 3);  // group (b,kvh,hh) per XCD
  const int j    = lg & 63;
  const int hh   = (lg >> 6) & 1;
  const int kvh  = (lg >> 7) & 1;
  const int b    = lg >> 8;
  const int hq   = kvh * 8 + hh * 4 + w;
  const f16 SCL2 = (f16)(0.08838834764831845f * 1.44269504088896f);  // 1/sqrt(128)*log2(e)

  const f16* Kb = K  + (size_t)b * S_ * DKV_ + kvh * DH_;
  const f16* Vb = V4 + (size_t)b * S_ * DKV_ + kvh * 512;

  auto stage = [&](int t32, int buf) {   // exactly 4 vm loads per thread
#pragma unroll
    for (int p2 = 0; p2 < 2; ++p2) {
      int ci = p2 * 256 + tid;
      int r = ci >> 4, cs = ci & 15;
      gload_lds16(Kb + (size_t)(t32 * 32 + r) * DKV_ + ((cs ^ (r & 7)) * 8),
                  (char*)&sK[buf][0] + p2 * 4096 + w * 1024);
      int g = ci >> 6, cc = ci & 63;
      gload_lds16(Vb + (size_t)(t32 * 8 + g) * 1024 + ((cc ^ g) * 8),
                  (char*)&sV[buf][0] + p2 * 4096 + w * 1024);
    }
  };

  for (int task = 0; task < 2; ++task) {
    const int qt  = task ? (127 - j) : j;
    const int n32 = (qt >> 1) + 1;
    const int q_pos = qt * 16 + qi;

    const size_t qbase = ((size_t)(b * S_ + qt * 16 + qi)) * D_ + hq * DH_;
    f16x8 qf[4];
#pragma unroll
    for (int kd = 0; kd < 4; ++kd) {
      qf[kd] = *reinterpret_cast<const f16x8*>(Q + qbase + kd * 32 + grp * 8);
#pragma unroll
      for (int e = 0; e < 8; ++e) qf[kd][e] *= SCL2;
    }

    float m = -INFINITY, lsum = 0.f;
    f32x4 accO[8] = {};

    stage(0, 0);
    stage(1, 1);
    asm volatile("s_waitcnt vmcnt(4)" ::: "memory");   // tile0 landed
    __builtin_amdgcn_s_barrier();

    for (int t = 0; t < n32; ++t) {
      const int buf = t & 3;
      const bool more = (t + 2 < n32);
      if (more) stage(t + 2, (t + 2) & 3);

      const int kv0 = t * 32;
      const f16* sKb = &sK[buf][0];
      const f16* sVb = &sV[buf][0];

      // QK^T (swapped): s{0,1}[jj] = S^T[kv0+half*16+grp*4+jj][q=qi], log2 units
      f32x4 s0 = {}, s1 = {};
#pragma unroll
      for (int kd = 0; kd < 4; ++kd) {
        const int cx = ((kd * 4 + grp) ^ (qi & 7)) << 3;
        f16x8 k0 = *reinterpret_cast<const f16x8*>(sKb + qi * 128 + cx);
        f16x8 k1 = *reinterpret_cast<const f16x8*>(sKb + (16 + qi) * 128 + cx);
        s0 = __builtin_amdgcn_mfma_f32_16x16x32_f16(k0, qf[kd], s0, 0, 0, 0);
        s1 = __builtin_amdgcn_mfma_f32_16x16x32_f16(k1, qf[kd], s1, 0, 0, 0);
      }
      float p[8];
#pragma unroll
      for (int jj = 0; jj < 4; ++jj) { p[jj] = s0[jj]; p[4 + jj] = s1[jj]; }
      if (t == n32 - 1) {              // only the last tile can cross the diagonal
#pragma unroll
        for (int jj = 0; jj < 4; ++jj) {
          int kvp = kv0 + grp * 4 + jj;
          p[jj]     = (kvp > q_pos)      ? -INFINITY : p[jj];
          p[4 + jj] = (kvp + 16 > q_pos) ? -INFINITY : p[4 + jj];
        }
      }
      float tm = -INFINITY;
#pragma unroll
      for (int i = 0; i < 8; ++i) tm = fmaxf(tm, p[i]);
      tm = fmaxf(tm, __shfl_xor(tm, 16));
      tm = fmaxf(tm, __shfl_xor(tm, 32));
      if (!__all(tm <= m + 8.f)) {     // defer-max: rescale only on real growth
        float mn = fmaxf(m, tm);
        float sc = exp2f(m - mn);
        m = mn;
        lsum *= sc;
#pragma unroll
        for (int dt = 0; dt < 8; ++dt)
#pragma unroll
          for (int jj = 0; jj < 4; ++jj) accO[dt][jj] *= sc;
      }
      float ps = 0.f;
#pragma unroll
      for (int i = 0; i < 8; ++i) {
        p[i] = exp2f(p[i] - m);
        ps += p[i];
      }
      lsum += ps;                      // per-lane partial, reduced at task end

      f16x4 pf0 = { (f16)p[0], (f16)p[1], (f16)p[2], (f16)p[3] };
      f16x4 pf1 = { (f16)p[4], (f16)p[5], (f16)p[6], (f16)p[7] };
#pragma unroll
      for (int dt = 0; dt < 8; ++dt) {
        const int dl = dt * 16 + qi;
        const int c  = dl >> 1;
        f16x4 v0 = *reinterpret_cast<const f16x4*>(
            sVb + grp * 512 + ((c ^ grp) << 3) + (dl & 1) * 4);
        f16x4 v1 = *reinterpret_cast<const f16x4*>(
            sVb + (grp + 4) * 512 + ((c ^ (grp + 4)) << 3) + (dl & 1) * 4);
        accO[dt] = __builtin_amdgcn_mfma_f32_16x16x16f16(v0, pf0, accO[dt], 0, 0, 0);
        accO[dt] = __builtin_amdgcn_mfma_f32_16x16x16f16(v1, pf1, accO[dt], 0, 0, 0);
      }

      if (more) { asm volatile("s_waitcnt vmcnt(4)" ::: "memory"); }  // tile t+1 landed
      else      { asm volatile("s_waitcnt vmcnt(0)" ::: "memory"); }
      __builtin_amdgcn_s_barrier();
    }

    lsum += __shfl_xor(lsum, 16);
    lsum += __shfl_xor(lsum, 32);
    float inv_l = 1.f / lsum;
    const size_t obase = ((size_t)(b * S_ + qt * 16 + qi)) * D_ + hq * DH_;
#pragma unroll
    for (int dt = 0; dt < 8; ++dt) {
      f16x4 st;
#pragma unroll
      for (int jj = 0; jj < 4; ++jj) st[jj] = (f16)(accO[dt][jj] * inv_l);
      *reinterpret_cast<f16x4*>(&O[obase + dt * 16 + grp * 4]) = st;
    }
  }
}

extern "C" void kernel_launch(void* const* d_in, const int* in_sizes, int n_in,
                              void* d_out, int out_size, void* d_ws, size_t ws_size,
                              hipStream_t stream) {
  const float* x  = (const float*)d_in[0];
  const float* Wq = (const float*)d_in[1];
  const float* bq = (const float*)d_in[2];
  const float* Wk = (const float*)d_in[3];
  const float* bk = (const float*)d_in[4];
  const float* Wv = (const float*)d_in[5];
  const float* bv = (const float*)d_in[6];
  const float* Wo = (const float*)d_in[7];
  const float* bo = (const float*)d_in[8];
  float* out = (float*)d_out;

  char* ws = (char*)d_ws;
  size_t off = 0;
  auto alloc = [&](size_t bytes) {
    char* p = ws + off;
    off += (bytes + 255) & ~(size_t)255;
    return p;
  };
  f16*   xh    = (f16*)alloc((size_t)B_ * S_ * D_ * 2);
  f16*   wqkv  = (f16*)alloc((size_t)NQKV_ * D_ * 2);
  f16*   woh   = (f16*)alloc((size_t)D_ * D_ * 2);
  f16*   qh    = (f16*)alloc((size_t)B_ * S_ * D_ * 2);
  f16*   kh    = (f16*)alloc((size_t)B_ * S_ * DKV_ * 2);
  f16*   v4h   = (f16*)alloc((size_t)B_ * S_ * DKV_ * 2);
  f16*   ah    = (f16*)alloc((size_t)B_ * S_ * D_ * 2);
  float* bqkv  = (float*)alloc((size_t)NQKV_ * 4);

  auto cast = [&](const float* in, f16* o, int n) {
    int n4 = n / 4;
    int grid = (n4 + 255) / 256;
    if (grid > 2048) grid = 2048;
    cast_kernel<<<dim3(grid), dim3(256), 0, stream>>>(in, o, n4);
  };
  cast(x,  xh, B_ * S_ * D_);
  cast(Wq, wqkv,                               D_ * D_);
  cast(Wk, wqkv + (size_t)D_ * D_,             DKV_ * D_);
  cast(Wv, wqkv + (size_t)(D_ + DKV_) * D_,    DKV_ * D_);
  cast(Wo, woh, D_ * D_);
  (void)hipMemcpyAsync(bqkv,             bq, D_ * 4,   hipMemcpyDeviceToDevice, stream);
  (void)hipMemcpyAsync(bqkv + D_,        bk, DKV_ * 4, hipMemcpyDeviceToDevice, stream);
  (void)hipMemcpyAsync(bqkv + D_ + DKV_, bv, DKV_ * 4, hipMemcpyDeviceToDevice, stream);

  const int M = B_ * S_;
  gemm_core<1><<<dim3((M / 128) * (NQKV_ / 128)), 256, 0, stream>>>(
      xh, wqkv, bqkv, qh, kh, v4h, nullptr, M, NQKV_, D_, NQKV_ / 128);

  attn_kernel<<<dim3(512), 256, 0, stream>>>(qh, kh, v4h, ah);

  gemm_core<0><<<dim3((M / 128) * (D_ / 128)), 256, 0, stream>>>(
      ah, woh, bo, nullptr, nullptr, nullptr, out, M, D_, D_, D_ / 128);
}